// Round 3
// baseline (716.424 us; speedup 1.0000x reference)
//
#include <hip/hip_runtime.h>

#define N_NODES 100000
#define R_REL   8
#define D_DIM   64
#define E_EDGES 3200000
#define NSEG    (N_NODES * R_REL)             // 800000
#define SCAN_BLOCKS 196                        // ceil(800000 / 4096)

typedef __attribute__((ext_vector_type(8))) short short8;   // 8 bf16 (4 VGPRs)
typedef __attribute__((ext_vector_type(4))) float f32x4;

__device__ __forceinline__ unsigned short f2bf(float f) {   // RNE float->bf16
    unsigned u = __float_as_uint(f);
    u += 0x7fffu + ((u >> 16) & 1u);
    return (unsigned short)(u >> 16);
}

// --- emb fp32 -> bf16 ------------------------------------------------------
__global__ void __launch_bounds__(256)
cvt_kernel(const float* __restrict__ in, unsigned short* __restrict__ outb) {
    size_t base = ((size_t)blockIdx.x * 256 + threadIdx.x) * 8;
    float4 v0 = *(const float4*)(in + base);
    float4 v1 = *(const float4*)(in + base + 4);
    uint4 o;
    o.x = f2bf(v0.x) | ((unsigned)f2bf(v0.y) << 16);
    o.y = f2bf(v0.z) | ((unsigned)f2bf(v0.w) << 16);
    o.z = f2bf(v1.x) | ((unsigned)f2bf(v1.y) << 16);
    o.w = f2bf(v1.z) | ((unsigned)f2bf(v1.w) << 16);
    *(uint4*)(outb + base) = o;
}

// --- CSR build: global counting sort over seg = dst*8 + rel ---------------
__global__ void __launch_bounds__(256)
hist_kernel(const int* __restrict__ dst, const int* __restrict__ et,
            int* __restrict__ cnt) {
    int e = blockIdx.x * 256 + threadIdx.x;               // grid exact: E/256
    atomicAdd(&cnt[dst[e] * 8 + et[e]], 1);
}

__global__ void __launch_bounds__(256)
scan1_kernel(const int* __restrict__ cnt, int* __restrict__ starts,
             int* __restrict__ partials) {
    __shared__ int sl[256];
    int t = threadIdx.x;
    int base = blockIdx.x * 4096 + t * 16;
    int v[16];
    int s = 0;
#pragma unroll
    for (int i = 0; i < 16; ++i) {
        int idx = base + i;
        v[i] = (idx < NSEG) ? cnt[idx] : 0;
        s += v[i];
    }
    sl[t] = s;
    __syncthreads();
    for (int off = 1; off < 256; off <<= 1) {
        int x = (t >= off) ? sl[t - off] : 0;
        __syncthreads();
        sl[t] += x;
        __syncthreads();
    }
    int run = (t == 0) ? 0 : sl[t - 1];
    if (t == 255) partials[blockIdx.x] = sl[255];
#pragma unroll
    for (int i = 0; i < 16; ++i) {
        int idx = base + i;
        if (idx < NSEG) starts[idx] = run;
        run += v[i];
    }
}

__global__ void scan2_kernel(int* __restrict__ partials) {
    __shared__ int sl[256];
    int t = threadIdx.x;
    int v = (t < SCAN_BLOCKS) ? partials[t] : 0;
    sl[t] = v;
    __syncthreads();
    for (int off = 1; off < 256; off <<= 1) {
        int x = (t >= off) ? sl[t - off] : 0;
        __syncthreads();
        sl[t] += x;
        __syncthreads();
    }
    if (t < SCAN_BLOCKS) partials[t] = sl[t] - v;         // exclusive
}

__global__ void __launch_bounds__(256)
scan3_kernel(int* __restrict__ starts, int* __restrict__ ends,
             const int* __restrict__ partials) {
    int t = threadIdx.x;
    int off = partials[blockIdx.x];
    int base = blockIdx.x * 4096 + t * 16;
#pragma unroll
    for (int i = 0; i < 16; ++i) {
        int idx = base + i;
        if (idx < NSEG) {
            int s = starts[idx] + off;
            starts[idx] = s;
            ends[idx] = s;                                 // cursor init
        }
    }
}

__global__ void __launch_bounds__(256)
scatter_kernel(const int* __restrict__ src, const int* __restrict__ dst,
               const int* __restrict__ et, int* __restrict__ ends,
               int* __restrict__ esrc) {
    int e = blockIdx.x * 256 + threadIdx.x;               // grid exact: E/256
    int pos = atomicAdd(&ends[dst[e] * 8 + et[e]], 1);    // ends -> start+cnt
    esrc[pos] = src[e];
}

// --- W prep: transpose W[r][k][d] -> wbuf[r][d][k] in bf16 (r=8 is root) ----
__global__ void wprep_kernel(const float* __restrict__ W, const float* __restrict__ root,
                             unsigned short* __restrict__ wbuf) {
    int r = blockIdx.x;
    const float* src = (r < 8) ? (W + (size_t)r * 4096) : root;
    __shared__ float t[64][65];
    int a = threadIdx.x >> 2, c = threadIdx.x & 3;
#pragma unroll
    for (int i = 0; i < 4; ++i) {
        float4 v = *(const float4*)(src + a * 64 + c * 16 + i * 4);
        t[a][c * 16 + i * 4 + 0] = v.x;
        t[a][c * 16 + i * 4 + 1] = v.y;
        t[a][c * 16 + i * 4 + 2] = v.z;
        t[a][c * 16 + i * 4 + 3] = v.w;
    }
    __syncthreads();
    unsigned short* outrow = wbuf + (size_t)r * 4096 + a * 64;
#pragma unroll
    for (int i = 0; i < 4; ++i) {
        int k0 = c * 16 + i * 4;
        ushort4 o;
        o.x = f2bf(t[k0 + 0][a]); o.y = f2bf(t[k0 + 1][a]);
        o.z = f2bf(t[k0 + 2][a]); o.w = f2bf(t[k0 + 3][a]);
        *(ushort4*)(outrow + k0) = o;
    }
}

// --- fused layer v3: stream-gather with 8-deep row-load batches ------------
// 16-lane group g owns node n0+g. Its 8 relation segments are CONTIGUOUS in
// esrc (global counting sort by seg = node*8+rel). The gather streams the
// whole run in batches of 8 independent hb-row loads (high MLP), flushing
// per-relation means at register-tracked boundaries (uniform branches; the
// 8 boundary values live in int4 regs, selected by static ternary chain).
// Then 9 MFMA phases back-to-back after ONE barrier.
__global__ void __launch_bounds__(512, 6)
fused_kernel(const unsigned short* __restrict__ hb, const int* __restrict__ esrc,
             const int* __restrict__ starts, const int* __restrict__ ends,
             const unsigned short* __restrict__ wbuf, const float* __restrict__ bias,
             void* __restrict__ out, int mode) {
    __shared__ unsigned short As[8][32][72];               // 36.9 KB
    int tid = threadIdx.x;
    int g   = tid >> 4;                                    // group 0..31 == local node
    int ml  = tid & 15;                                    // dim lane: dims 4ml..4ml+3
    int n0  = blockIdx.x * 32;

    // ---- gather: stream node (n0+g)'s full edge run ----
    {
        int segb = (n0 + g) * R_REL;
        int4 eA = *(const int4*)(ends + segb);             // ends[segb+0..3]
        int4 eB = *(const int4*)(ends + segb + 4);         // ends[segb+4..7]
        int beg_cur = starts[segb];
        int end_cur = eA.x;
        int eN = eB.w;
        int r = 0;
        float a0 = 0.f, a1 = 0.f, a2 = 0.f, a3 = 0.f;

#define FLUSH()                                                          \
    do {                                                                 \
        float inv = 1.0f / fmaxf((float)(end_cur - beg_cur), 1.0f);      \
        ushort4 o;                                                       \
        o.x = f2bf(a0 * inv); o.y = f2bf(a1 * inv);                      \
        o.z = f2bf(a2 * inv); o.w = f2bf(a3 * inv);                      \
        *(ushort4*)(&As[r][g][ml * 4]) = o;                              \
        a0 = a1 = a2 = a3 = 0.f;                                         \
        ++r;                                                             \
        beg_cur = end_cur;                                               \
        end_cur = (r == 1) ? eA.y : (r == 2) ? eA.z : (r == 3) ? eA.w :  \
                  (r == 4) ? eB.x : (r == 5) ? eB.y : (r == 6) ? eB.z :  \
                  (r == 7) ? eB.w : 0x7fffffff;                          \
    } while (0)

        int e = beg_cur;
        while (e < eN) {
            int m = eN - e; if (m > 8) m = 8;
            int ids[8];
#pragma unroll
            for (int i = 0; i < 8; ++i) ids[i] = esrc[e + (i < m ? i : 0)];
            uint2 rows[8];
#pragma unroll
            for (int i = 0; i < 8; ++i)
                rows[i] = *(const uint2*)(hb + (size_t)ids[i] * D_DIM + ml * 4);
#pragma unroll
            for (int i = 0; i < 8; ++i) {
                if (i < m) {
                    while (e + i >= end_cur) FLUSH();
                    a0 += __uint_as_float(rows[i].x << 16);
                    a1 += __uint_as_float(rows[i].x & 0xffff0000u);
                    a2 += __uint_as_float(rows[i].y << 16);
                    a3 += __uint_as_float(rows[i].y & 0xffff0000u);
                }
            }
            e += m;
        }
        while (r < 8) FLUSH();
#undef FLUSH
    }

    // ---- wave/fragment ids for MFMA ----
    int w  = tid >> 6;                                     // wave 0..7
    int kg = g & 3;                                        // k-group within wave
    int h  = w & 1;                                        // node-half (16 nodes)
    int q  = w >> 1;                                       // dim-quarter (16 dims)

    // root A-fragments direct from global (latency hides under MFMA phases)
    const unsigned short* rp = hb + (size_t)(n0 + h * 16 + ml) * D_DIM + kg * 8;
    short8 RA0 = *(const short8*)(rp);
    short8 RA1 = *(const short8*)(rp + 32);

    __syncthreads();                                       // the ONLY barrier

    f32x4 acc = {0, 0, 0, 0};
#pragma unroll 1
    for (int p = 0; p < 8; ++p) {
        short8 A0 = *(const short8*)(&As[p][h * 16 + ml][kg * 8]);
        short8 A1 = *(const short8*)(&As[p][h * 16 + ml][kg * 8 + 32]);
        const unsigned short* bp = wbuf + (size_t)p * 4096 + (q * 16 + ml) * 64 + kg * 8;
        short8 B0 = *(const short8*)(bp);                  // L1/L2-hot
        short8 B1 = *(const short8*)(bp + 32);
        acc = __builtin_amdgcn_mfma_f32_16x16x32_bf16(A0, B0, acc, 0, 0, 0);
        acc = __builtin_amdgcn_mfma_f32_16x16x32_bf16(A1, B1, acc, 0, 0, 0);
    }
    {   // root phase
        const unsigned short* bp = wbuf + (size_t)8 * 4096 + (q * 16 + ml) * 64 + kg * 8;
        short8 B0 = *(const short8*)(bp);
        short8 B1 = *(const short8*)(bp + 32);
        acc = __builtin_amdgcn_mfma_f32_16x16x32_bf16(RA0, B0, acc, 0, 0, 0);
        acc = __builtin_amdgcn_mfma_f32_16x16x32_bf16(RA1, B1, acc, 0, 0, 0);
    }

    // epilogue: C layout col=ml (dim), row=kg*4+reg (node) [verified]
    float bv = bias[q * 16 + ml];
#pragma unroll
    for (int rg = 0; rg < 4; ++rg) {
        int node = n0 + h * 16 + kg * 4 + rg;
        float v = acc[rg] + bv;
        if (mode) {
            v = fmaxf(v, 0.f);
            ((unsigned short*)out)[(size_t)node * D_DIM + q * 16 + ml] = f2bf(v);
        } else {
            ((float*)out)[(size_t)node * D_DIM + q * 16 + ml] = v;
        }
    }
}

// --- launch ---------------------------------------------------------------

extern "C" void kernel_launch(void* const* d_in, const int* in_sizes, int n_in,
                              void* d_out, int out_size, void* d_ws, size_t ws_size,
                              hipStream_t stream) {
    const int*   ei    = (const int*)d_in[1];
    const int*   src   = ei;
    const int*   dst   = ei + E_EDGES;
    const int*   et    = (const int*)d_in[2];
    const float* emb   = (const float*)d_in[3];   // x = arange(N): identity remap
    const float* W1    = (const float*)d_in[4];
    const float* root1 = (const float*)d_in[5];
    const float* b1    = (const float*)d_in[6];
    const float* W2    = (const float*)d_in[7];
    const float* root2 = (const float*)d_in[8];
    const float* b2    = (const float*)d_in[9];
    float*       out   = (float*)d_out;

    // workspace layout (bf16 blocks first: all 16B-aligned)
    unsigned short* embb   = (unsigned short*)d_ws;                      // [N*64] bf16
    unsigned short* h1b    = embb + (size_t)N_NODES * D_DIM;             // [N*64] bf16
    unsigned short* wbuf1  = h1b + (size_t)N_NODES * D_DIM;              // [9*4096] bf16
    unsigned short* wbuf2  = wbuf1 + 9 * 4096;
    int*            starts = (int*)(wbuf2 + 9 * 4096);                   // [NSEG]
    int*            ends   = starts + NSEG;                              // [NSEG]
    int*            cnt    = ends + NSEG;                                // [NSEG]
    int*            esrc   = cnt + NSEG;                                 // [E]
    int*            partials = esrc + E_EDGES;                           // [256]

    // ---- CSR build: global counting sort over (dst, rel) ----
    hipMemsetAsync(cnt, 0, (size_t)NSEG * sizeof(int), stream);
    hist_kernel   <<<E_EDGES / 256, 256, 0, stream>>>(dst, et, cnt);
    scan1_kernel  <<<SCAN_BLOCKS, 256, 0, stream>>>(cnt, starts, partials);
    scan2_kernel  <<<1, 256, 0, stream>>>(partials);
    scan3_kernel  <<<SCAN_BLOCKS, 256, 0, stream>>>(starts, ends, partials);
    scatter_kernel<<<E_EDGES / 256, 256, 0, stream>>>(src, dst, et, ends, esrc);

    // ---- prep: weights (bf16 transposed) + emb bf16 copy ----
    wprep_kernel<<<9, 256, 0, stream>>>(W1, root1, wbuf1);
    wprep_kernel<<<9, 256, 0, stream>>>(W2, root2, wbuf2);
    cvt_kernel<<<(N_NODES * D_DIM) / 2048, 256, 0, stream>>>(emb, embb);

    const int blocks = N_NODES / 32;             // 3125 exact

    // ---- layer 1: emb -> h1b (ReLU, bf16) ----
    fused_kernel<<<blocks, 512, 0, stream>>>(embb, esrc, starts, ends, wbuf1, b1, h1b, 1);
    // ---- layer 2: h1b -> out (fp32) ----
    fused_kernel<<<blocks, 512, 0, stream>>>(h1b, esrc, starts, ends, wbuf2, b2, out, 0);
}

// Round 4
// 440.957 us; speedup vs baseline: 1.6247x; 1.6247x over previous
//
#include <hip/hip_runtime.h>

#define N_NODES 100000
#define R_REL   8
#define D_DIM   64
#define E_EDGES 3200000
#define NSEG    (N_NODES * R_REL)             // 800000
#define NB      782                            // dst buckets (dst>>7)
#define SEG_PER_BKT 1024                       // 128 nodes * 8 rel
#define BKT_CAP 4800                           // mean 4092 + ~11 sigma
#define P1_BLOCKS 512
#define P1_CHUNK  (E_EDGES / P1_BLOCKS)        // 6250

typedef __attribute__((ext_vector_type(8))) short short8;   // 8 bf16 (4 VGPRs)
typedef __attribute__((ext_vector_type(4))) float f32x4;

__device__ __forceinline__ unsigned short f2bf(float f) {   // RNE float->bf16
    unsigned u = __float_as_uint(f);
    u += 0x7fffu + ((u >> 16) & 1u);
    return (unsigned short)(u >> 16);
}

__device__ __forceinline__ int epack(int s, int d, int r) {
    return (s << 10) | ((d & 127) << 3) | r;
}

// --- emb fp32 -> bf16 ------------------------------------------------------
__global__ void __launch_bounds__(256)
cvt_kernel(const float* __restrict__ in, unsigned short* __restrict__ outb) {
    size_t base = ((size_t)blockIdx.x * 256 + threadIdx.x) * 8;
    float4 v0 = *(const float4*)(in + base);
    float4 v1 = *(const float4*)(in + base + 4);
    uint4 o;
    o.x = f2bf(v0.x) | ((unsigned)f2bf(v0.y) << 16);
    o.y = f2bf(v0.z) | ((unsigned)f2bf(v0.w) << 16);
    o.z = f2bf(v1.x) | ((unsigned)f2bf(v1.y) << 16);
    o.w = f2bf(v1.z) | ((unsigned)f2bf(v1.w) << 16);
    *(uint4*)(outb + base) = o;
}

// --- bucket cursor init: bkt_cursor[b] = b*CAP (fixed-capacity buckets) ----
__global__ void init_cursor_kernel(int* __restrict__ bkt_cursor) {
    int t = blockIdx.x * 256 + threadIdx.x;
    if (t <= NB) bkt_cursor[t] = t * BKT_CAP;
}

// --- P1: partition edges into fixed-capacity dst-buckets -------------------
__global__ void __launch_bounds__(256)
p1_scatter_kernel(const int* __restrict__ src, const int* __restrict__ dst,
                  const int* __restrict__ et, int* __restrict__ bkt_cursor,
                  int* __restrict__ packed) {
    __shared__ int hist[NB];
    __shared__ int cur[NB];
    int t = threadIdx.x;
    for (int i = t; i < NB; i += 256) hist[i] = 0;
    __syncthreads();
    int base = blockIdx.x * P1_CHUNK;
    for (int i = t; i < P1_CHUNK; i += 256)
        atomicAdd(&hist[dst[base + i] >> 7], 1);
    __syncthreads();
    for (int i = t; i < NB; i += 256) {
        int c = hist[i];
        cur[i] = c ? atomicAdd(&bkt_cursor[i], c) : 0;    // reserve block's run
    }
    __syncthreads();
    for (int i = t; i < P1_CHUNK; i += 256) {
        int e = base + i;
        int d = dst[e];
        int pos = atomicAdd(&cur[d >> 7], 1);
        packed[pos] = epack(src[e], d, et[e]);            // runs of ~8 -> line-merged
    }
}

// --- P2: per-bucket counting sort in LDS -> sorted esrc + starts/ends ------
__global__ void __launch_bounds__(256)
p2_sort_kernel(const int* __restrict__ packed, const int* __restrict__ bkt_cursor,
               int* __restrict__ starts, int* __restrict__ ends, int* __restrict__ esrc) {
    __shared__ int shist[SEG_PER_BKT];
    __shared__ int scur[SEG_PER_BKT];
    __shared__ int stmp[256];
    int b = blockIdx.x;
    int t = threadIdx.x;
    int ebase = b * BKT_CAP;
    int eend  = bkt_cursor[b];                            // == ebase + bucket count
    int segbase = b * SEG_PER_BKT;
    int nseg = NSEG - segbase; if (nseg > SEG_PER_BKT) nseg = SEG_PER_BKT;
#pragma unroll
    for (int i = 0; i < 4; ++i) shist[t + i * 256] = 0;
    __syncthreads();
    for (int e = ebase + t; e < eend; e += 256)
        atomicAdd(&shist[packed[e] & 1023], 1);
    __syncthreads();
    int loc[4], s = 0;
    int b4 = t * 4;
#pragma unroll
    for (int i = 0; i < 4; ++i) { loc[i] = shist[b4 + i]; s += loc[i]; }
    stmp[t] = s;
    __syncthreads();
    for (int off = 1; off < 256; off <<= 1) {
        int x = (t >= off) ? stmp[t - off] : 0;
        __syncthreads();
        stmp[t] += x;
        __syncthreads();
    }
    int run = (t == 0) ? 0 : stmp[t - 1];
#pragma unroll
    for (int i = 0; i < 4; ++i) {
        shist[b4 + i] = run; scur[b4 + i] = run;
        run += loc[i];
    }
    __syncthreads();
    for (int i = t; i < nseg; i += 256)
        starts[segbase + i] = ebase + shist[i];
    for (int e = ebase + t; e < eend; e += 256) {
        int p = packed[e];
        int r = atomicAdd(&scur[p & 1023], 1);
        esrc[ebase + r] = p >> 10;                        // 19KB window, L2-merged
    }
    __syncthreads();
    for (int i = t; i < nseg; i += 256)
        ends[segbase + i] = ebase + scur[i];              // scur = start + count now
}

// --- W prep: transpose W[r][k][d] -> wbuf[r][d][k] in bf16 (r=8 is root) ----
__global__ void wprep_kernel(const float* __restrict__ W, const float* __restrict__ root,
                             unsigned short* __restrict__ wbuf) {
    int r = blockIdx.x;
    const float* src = (r < 8) ? (W + (size_t)r * 4096) : root;
    __shared__ float t[64][65];
    int a = threadIdx.x >> 2, c = threadIdx.x & 3;
#pragma unroll
    for (int i = 0; i < 4; ++i) {
        float4 v = *(const float4*)(src + a * 64 + c * 16 + i * 4);
        t[a][c * 16 + i * 4 + 0] = v.x;
        t[a][c * 16 + i * 4 + 1] = v.y;
        t[a][c * 16 + i * 4 + 2] = v.z;
        t[a][c * 16 + i * 4 + 3] = v.w;
    }
    __syncthreads();
    unsigned short* outrow = wbuf + (size_t)r * 4096 + a * 64;
#pragma unroll
    for (int i = 0; i < 4; ++i) {
        int k0 = c * 16 + i * 4;
        ushort4 o;
        o.x = f2bf(t[k0 + 0][a]); o.y = f2bf(t[k0 + 1][a]);
        o.z = f2bf(t[k0 + 2][a]); o.w = f2bf(t[k0 + 3][a]);
        *(ushort4*)(outrow + k0) = o;
    }
}

// --- fused layer v3: stream-gather with 8-deep row-load batches ------------
// 16-lane group g owns node n0+g. Its 8 relation segments are CONTIGUOUS in
// esrc (bucketed counting sort; node's bucket = node>>7, local seg =
// (node&127)*8+rel, so starts/ends index as node*8+rel and the node's run
// is contiguous within its bucket). Gather streams the whole run in batches
// of 8 independent hb-row loads (high MLP), flushing per-relation means at
// register-tracked boundaries. Then 9 MFMA phases after ONE barrier.
__global__ void __launch_bounds__(512, 6)
fused_kernel(const unsigned short* __restrict__ hb, const int* __restrict__ esrc,
             const int* __restrict__ starts, const int* __restrict__ ends,
             const unsigned short* __restrict__ wbuf, const float* __restrict__ bias,
             void* __restrict__ out, int mode) {
    __shared__ unsigned short As[8][32][72];               // 36.9 KB
    int tid = threadIdx.x;
    int g   = tid >> 4;                                    // group 0..31 == local node
    int ml  = tid & 15;                                    // dim lane: dims 4ml..4ml+3
    int n0  = blockIdx.x * 32;

    // ---- gather: stream node (n0+g)'s full edge run ----
    {
        int segb = (n0 + g) * R_REL;
        int4 eA = *(const int4*)(ends + segb);             // ends[segb+0..3]
        int4 eB = *(const int4*)(ends + segb + 4);         // ends[segb+4..7]
        int beg_cur = starts[segb];
        int end_cur = eA.x;
        int eN = eB.w;
        int r = 0;
        float a0 = 0.f, a1 = 0.f, a2 = 0.f, a3 = 0.f;

#define FLUSH()                                                          \
    do {                                                                 \
        float inv = 1.0f / fmaxf((float)(end_cur - beg_cur), 1.0f);      \
        ushort4 o;                                                       \
        o.x = f2bf(a0 * inv); o.y = f2bf(a1 * inv);                      \
        o.z = f2bf(a2 * inv); o.w = f2bf(a3 * inv);                      \
        *(ushort4*)(&As[r][g][ml * 4]) = o;                              \
        a0 = a1 = a2 = a3 = 0.f;                                         \
        ++r;                                                             \
        beg_cur = end_cur;                                               \
        end_cur = (r == 1) ? eA.y : (r == 2) ? eA.z : (r == 3) ? eA.w :  \
                  (r == 4) ? eB.x : (r == 5) ? eB.y : (r == 6) ? eB.z :  \
                  (r == 7) ? eB.w : 0x7fffffff;                          \
    } while (0)

        int e = beg_cur;
        while (e < eN) {
            int m = eN - e; if (m > 8) m = 8;
            int ids[8];
#pragma unroll
            for (int i = 0; i < 8; ++i) ids[i] = esrc[e + (i < m ? i : 0)];
            uint2 rows[8];
#pragma unroll
            for (int i = 0; i < 8; ++i)
                rows[i] = *(const uint2*)(hb + (size_t)ids[i] * D_DIM + ml * 4);
#pragma unroll
            for (int i = 0; i < 8; ++i) {
                if (i < m) {
                    while (e + i >= end_cur) FLUSH();
                    a0 += __uint_as_float(rows[i].x << 16);
                    a1 += __uint_as_float(rows[i].x & 0xffff0000u);
                    a2 += __uint_as_float(rows[i].y << 16);
                    a3 += __uint_as_float(rows[i].y & 0xffff0000u);
                }
            }
            e += m;
        }
        while (r < 8) FLUSH();
#undef FLUSH
    }

    // ---- wave/fragment ids for MFMA ----
    int w  = tid >> 6;                                     // wave 0..7
    int kg = g & 3;                                        // k-group within wave
    int h  = w & 1;                                        // node-half (16 nodes)
    int q  = w >> 1;                                       // dim-quarter (16 dims)

    // root A-fragments direct from global (latency hides under MFMA phases)
    const unsigned short* rp = hb + (size_t)(n0 + h * 16 + ml) * D_DIM + kg * 8;
    short8 RA0 = *(const short8*)(rp);
    short8 RA1 = *(const short8*)(rp + 32);

    __syncthreads();                                       // the ONLY barrier

    f32x4 acc = {0, 0, 0, 0};
#pragma unroll 1
    for (int p = 0; p < 8; ++p) {
        short8 A0 = *(const short8*)(&As[p][h * 16 + ml][kg * 8]);
        short8 A1 = *(const short8*)(&As[p][h * 16 + ml][kg * 8 + 32]);
        const unsigned short* bp = wbuf + (size_t)p * 4096 + (q * 16 + ml) * 64 + kg * 8;
        short8 B0 = *(const short8*)(bp);                  // L1/L2-hot
        short8 B1 = *(const short8*)(bp + 32);
        acc = __builtin_amdgcn_mfma_f32_16x16x32_bf16(A0, B0, acc, 0, 0, 0);
        acc = __builtin_amdgcn_mfma_f32_16x16x32_bf16(A1, B1, acc, 0, 0, 0);
    }
    {   // root phase
        const unsigned short* bp = wbuf + (size_t)8 * 4096 + (q * 16 + ml) * 64 + kg * 8;
        short8 B0 = *(const short8*)(bp);
        short8 B1 = *(const short8*)(bp + 32);
        acc = __builtin_amdgcn_mfma_f32_16x16x32_bf16(RA0, B0, acc, 0, 0, 0);
        acc = __builtin_amdgcn_mfma_f32_16x16x32_bf16(RA1, B1, acc, 0, 0, 0);
    }

    // epilogue: C layout col=ml (dim), row=kg*4+reg (node) [verified]
    float bv = bias[q * 16 + ml];
#pragma unroll
    for (int rg = 0; rg < 4; ++rg) {
        int node = n0 + h * 16 + kg * 4 + rg;
        float v = acc[rg] + bv;
        if (mode) {
            v = fmaxf(v, 0.f);
            ((unsigned short*)out)[(size_t)node * D_DIM + q * 16 + ml] = f2bf(v);
        } else {
            ((float*)out)[(size_t)node * D_DIM + q * 16 + ml] = v;
        }
    }
}

// --- launch ---------------------------------------------------------------

extern "C" void kernel_launch(void* const* d_in, const int* in_sizes, int n_in,
                              void* d_out, int out_size, void* d_ws, size_t ws_size,
                              hipStream_t stream) {
    const int*   ei    = (const int*)d_in[1];
    const int*   src   = ei;
    const int*   dst   = ei + E_EDGES;
    const int*   et    = (const int*)d_in[2];
    const float* emb   = (const float*)d_in[3];   // x = arange(N): identity remap
    const float* W1    = (const float*)d_in[4];
    const float* root1 = (const float*)d_in[5];
    const float* b1    = (const float*)d_in[6];
    const float* W2    = (const float*)d_in[7];
    const float* root2 = (const float*)d_in[8];
    const float* b2    = (const float*)d_in[9];
    float*       out   = (float*)d_out;

    // workspace layout (bf16 blocks first: all 16B-aligned)
    unsigned short* embb   = (unsigned short*)d_ws;                      // [N*64] bf16
    unsigned short* h1b    = embb + (size_t)N_NODES * D_DIM;             // [N*64] bf16
    unsigned short* wbuf1  = h1b + (size_t)N_NODES * D_DIM;              // [9*4096] bf16
    unsigned short* wbuf2  = wbuf1 + 9 * 4096;
    int*            starts = (int*)(wbuf2 + 9 * 4096);                   // [NSEG]
    int*            ends   = starts + NSEG;                              // [NSEG]
    int*            packed = ends + NSEG;                                // [NB*CAP]
    int*            esrc   = packed + (size_t)NB * BKT_CAP;              // [NB*CAP]
    int*            bkt_cursor = esrc + (size_t)NB * BKT_CAP;            // [NB+1]

    // ---- CSR build: fixed-capacity buckets, no global hist/scan ----
    init_cursor_kernel<<<4, 256, 0, stream>>>(bkt_cursor);
    p1_scatter_kernel <<<P1_BLOCKS, 256, 0, stream>>>(src, dst, et, bkt_cursor, packed);
    p2_sort_kernel    <<<NB, 256, 0, stream>>>(packed, bkt_cursor, starts, ends, esrc);

    // ---- prep: weights (bf16 transposed) + emb bf16 copy ----
    wprep_kernel<<<9, 256, 0, stream>>>(W1, root1, wbuf1);
    wprep_kernel<<<9, 256, 0, stream>>>(W2, root2, wbuf2);
    cvt_kernel<<<(N_NODES * D_DIM) / 2048, 256, 0, stream>>>(emb, embb);

    const int blocks = N_NODES / 32;             // 3125 exact

    // ---- layer 1: emb -> h1b (ReLU, bf16) ----
    fused_kernel<<<blocks, 512, 0, stream>>>(embb, esrc, starts, ends, wbuf1, b1, h1b, 1);
    // ---- layer 2: h1b -> out (fp32) ----
    fused_kernel<<<blocks, 512, 0, stream>>>(h1b, esrc, starts, ends, wbuf2, b2, out, 0);
}